// Round 7
// baseline (334.389 us; speedup 1.0000x reference)
//
#include <hip/hip_runtime.h>
#include <stdint.h>

// Problem constants (static shapes from the reference)
constexpr int Bq = 2;
constexpr int Qn = 300;
constexpr int Cn = 80;
constexpr int Kn = 300;
constexpr int NFLAT = Qn * Cn;   // 24000
constexpr int MHs = 128;
constexpr int MWs = 128;
constexpr int THs = 320;
constexpr int TWs = 320;

// Output layout (flat concatenation in reference return order, all as float)
constexpr int OFF_SCORES = 0;                         // [B,K]     600
constexpr int OFF_LABELS = Bq * Kn;                   // [B,K]     600
constexpr int OFF_BOXES  = 2 * Bq * Kn;               // [B,K,4]   2400
constexpr int OFF_MASKS  = 2 * Bq * Kn + Bq * Kn * 4; // [B,K,320,320]

constexpr int TPB = 1024;
constexpr int EPT = (NFLAT + TPB - 1) / TPB;          // 24 elements/thread

typedef float vf4  __attribute__((ext_vector_type(4)));              // 16B-aligned
typedef float uvf4 __attribute__((ext_vector_type(4), aligned(4)));  // align-4 load

// ---------------------------------------------------------------------------
// Kernel A v6: per-batch top-K. Histogram in the LOGIT (linear) domain —
// 4096 bins over [-8,8] are nearly flat for ~N(0,1) logits (max ~40/bin), so
// LDS atomics don't serialize (the round-2 failure binned sigmoid FLOAT BITS,
// whose exponent compression put half the data in 32 bins). Suffix scan
// locates the rank-K bin; ~K+30 candidates are collected and ranked by count.
// Final ordering key is (sigmoid_bits<<32)|~idx — exact jax.lax.top_k
// semantics (desc score, ties -> lowest flat index).
// ---------------------------------------------------------------------------
__global__ __launch_bounds__(TPB) void topk_kernel(
    const float* __restrict__ logits,   // [B,Q,C]
    const float* __restrict__ boxes,    // [B,Q,4] cxcywh
    const float* __restrict__ osz,      // [B,2] (w,h)
    float* __restrict__ out,
    int* __restrict__ qidx_ws)          // [B,K]
{
    const int b   = blockIdx.x;
    const int tid = threadIdx.x;
    const float* lg = logits + (size_t)b * NFLAT;

    // Load logits once; bin index per element (clamped linear binning).
    float xv[EPT];
    short bn[EPT];
    #pragma unroll
    for (int j = 0; j < EPT; ++j) {
        int idx = j * TPB + tid;
        bool valid = (idx < NFLAT);
        float x = valid ? lg[idx] : -1e30f;
        xv[j] = x;
        int bi = (int)floorf((x + 8.0f) * 256.0f);   // [-8,8] -> [0,4096)
        bn[j] = (short)min(max(bi, 0), 4095);
        if (!valid) bn[j] = -1;
    }

    __shared__ int hist[4096];
    __shared__ int scanA[1024], scanB[1024];
    __shared__ unsigned long long sk[1024];
    __shared__ int s_cnt, s_seg, s_B;

    {
        int4* h4 = (int4*)hist;
        for (int i = tid; i < 4096 / 4; i += TPB) h4[i] = make_int4(0, 0, 0, 0);
    }
    if (tid == 0) s_cnt = 0;
    __syncthreads();

    #pragma unroll
    for (int j = 0; j < EPT; ++j)
        if (bn[j] >= 0) atomicAdd(&hist[bn[j]], 1);
    __syncthreads();

    // Suffix scan: thread t covers bins 4t..4t+3
    int sum = hist[4 * tid] + hist[4 * tid + 1] + hist[4 * tid + 2] + hist[4 * tid + 3];
    scanA[tid] = sum;
    __syncthreads();
    int* src = scanA;
    int* dst = scanB;
    for (int d = 1; d < 1024; d <<= 1) {
        int v = src[tid] + ((tid + d < 1024) ? src[tid + d] : 0);
        dst[tid] = v;
        __syncthreads();
        int* t = src; src = dst; dst = t;
    }
    // src[t] = count of elements with bin >= 4t

    int sfx  = src[tid];
    int sfx1 = (tid < 1023) ? src[tid + 1] : 0;
    if (sfx >= Kn && sfx1 < Kn) s_seg = tid;       // unique
    __syncthreads();

    if (tid == 0) {
        int t = s_seg;
        int cumAbove = (t < 1023) ? src[t + 1] : 0;
        int B = 4 * t;
        for (int i = 3; i >= 0; --i) {
            int bin = 4 * t + i;
            int c = hist[bin];
            if (cumAbove + c >= Kn) { B = bin; break; }
            cumAbove += c;
        }
        s_B = B;
    }
    __syncthreads();

    // Collect candidates (bin >= threshold bin): n in [300, ~340]
    const int Bv = s_B;
    #pragma unroll
    for (int j = 0; j < EPT; ++j) {
        if ((int)bn[j] >= Bv) {
            int idx = j * TPB + tid;
            float s = 1.0f / (1.0f + expf(-xv[j]));  // same formula as rounds 1-6
            int p = atomicAdd(&s_cnt, 1);
            if (p < 1024)
                sk[p] = ((unsigned long long)__float_as_uint(s) << 32)
                      | (unsigned long long)(0xFFFFFFFFu - (uint32_t)idx);
        }
    }
    __syncthreads();

    // Rank by count (unique keys => permutation; LDS broadcast reads)
    const int n = min(s_cnt, 1024);
    if (tid < n) {
        unsigned long long my = sk[tid];
        int rank = 0;
        for (int i = 0; i < n; ++i) rank += (sk[i] > my) ? 1 : 0;
        if (rank < Kn) {
            uint32_t idx = 0xFFFFFFFFu - (uint32_t)(my & 0xFFFFFFFFull);
            float score  = __uint_as_float((uint32_t)(my >> 32));
            int label = (int)(idx % (uint32_t)Cn);
            int q     = (int)(idx / (uint32_t)Cn);

            out[OFF_SCORES + b * Kn + rank] = score;
            out[OFF_LABELS + b * Kn + rank] = (float)label;

            const float sw = osz[b * 2 + 0];
            const float sh = osz[b * 2 + 1];
            const float* bx = boxes + ((size_t)(b * Qn + q)) * 4;
            float cx = bx[0], cy = bx[1], w = bx[2], h = bx[3];
            float* ob = out + OFF_BOXES + ((size_t)(b * Kn + rank)) * 4;
            ob[0] = (cx - 0.5f * w) * sw;
            ob[1] = (cy - 0.5f * h) * sh;
            ob[2] = (cx + 0.5f * w) * sw;
            ob[3] = (cy + 0.5f * h) * sh;

            qidx_ws[b * Kn + rank] = q;
        }
    }
}

// ---------------------------------------------------------------------------
// Kernel B v7: identical structure to v6 (lane = 4 consecutive output cols,
// contiguous full-line wave stores; ONE align-4 dwordx4 load per source row
// via per-lane zero-padded 4x4 x-weight table; period-5 y rotation) but with
// PLAIN float4 stores instead of nontemporal — NT bypasses L2 write-combining
// and is the last untested constant across the slow rounds 3-6; the harness
// fill kernel reaches 6.2 TB/s with plain stores through L2.
// ---------------------------------------------------------------------------
__global__ __launch_bounds__(320) void resize_kernel(
    const float* __restrict__ masks,    // [B,Q,128,128]
    const int* __restrict__ qidx_ws,    // [B,K]
    float* __restrict__ out)
{
    const int blk = blockIdx.x;
    const int bk  = blk >> 2;          // b*K + k
    const int s   = blk & 3;           // 80-row chunk
    const int tid = threadIdx.x;
    const int b   = bk / Kn;
    const int q   = qidx_ws[bk];
    const int c   = tid % 80;          // out cols 4c..4c+3
    const int rs  = tid / 80;          // 20-row slab within chunk

    const float* M = masks + ((size_t)(b * Qn + q)) * (MHs * MWs);

    // ---- x setup: source window base s0 and 4x4 zero-padded weight table
    int s0;
    {
        float sx0 = fmaf(0.4f, (float)(4 * c), -0.3f);
        int i0 = (int)floorf(sx0);
        s0 = min(max(i0, 0), MWs - 4);   // [0,124]
    }
    float W[4][4];
    #pragma unroll
    for (int t = 0; t < 4; ++t) {
        int ox = 4 * c + t;
        float sx = fmaf(0.4f, (float)ox, -0.3f);
        int ix0 = (int)floorf(sx);
        float fr = sx - (float)ix0;
        int ca = max(ix0, 0);
        int cb = min(ix0 + 1, MWs - 1);
        float wa = 1.0f - fr, wb = fr;
        #pragma unroll
        for (int j = 0; j < 4; ++j) {
            float w = 0.0f;
            if (s0 + j == ca) w += wa;
            if (s0 + j == cb) w += wb;
            W[t][j] = w;
        }
    }

    auto hrow = [&](float* hv, int r) {
        uvf4 a = *(const uvf4*)(M + r * MWs + s0);
        #pragma unroll
        for (int t = 0; t < 4; ++t)
            hv[t] = fmaf(W[t][0], a[0],
                    fmaf(W[t][1], a[1],
                    fmaf(W[t][2], a[2], W[t][3] * a[3])));
    };

    float* outm = out + OFF_MASKS + (size_t)bk * (THs * TWs);
    auto emit = [&](int row, float wA, const float* pA, float wB, const float* pB) {
        vf4 o;
        #pragma unroll
        for (int t = 0; t < 4; ++t) {
            float v = fmaf(wA, pA[t], wB * pB[t]);
            o[t] = (v > 0.0f) ? 1.0f : 0.0f;
        }
        *(vf4*)(outm + (size_t)row * TWs + 4 * c) = o;   // plain store (L2 WB)
    };

    const int Y0 = 80 * s + 20 * rs;   // first output row of this lane
    const int M0 = Y0 / 5;             // 16s + 4rs

    float hA[4], hB[4], hC[4], hD[4];
    hrow(hC, max(2 * M0 - 1, 0));
    hrow(hD, 2 * M0);

    #pragma unroll
    for (int g = 0; g < 4; ++g) {
        #pragma unroll
        for (int t = 0; t < 4; ++t) { hA[t] = hC[t]; hB[t] = hD[t]; }
        const int Mg = M0 + g;
        hrow(hC, 2 * Mg + 1);
        hrow(hD, min(2 * Mg + 2, MHs - 1));

        const int Y = Y0 + 5 * g;
        emit(Y + 0, 0.3f, hA, 0.7f, hB);   // phase 0: h[2m-1], h[2m]
        emit(Y + 1, 0.9f, hB, 0.1f, hC);   // phase 1: h[2m],  h[2m+1]
        emit(Y + 2, 0.5f, hB, 0.5f, hC);   // phase 2
        emit(Y + 3, 0.1f, hB, 0.9f, hC);   // phase 3
        emit(Y + 4, 0.7f, hC, 0.3f, hD);   // phase 4: h[2m+1], h[2m+2]
    }
}

// ---------------------------------------------------------------------------
extern "C" void kernel_launch(void* const* d_in, const int* in_sizes, int n_in,
                              void* d_out, int out_size, void* d_ws, size_t ws_size,
                              hipStream_t stream) {
    const float* logits = (const float*)d_in[0];   // [B,Q,C]
    const float* boxes  = (const float*)d_in[1];   // [B,Q,4]
    const float* masks  = (const float*)d_in[2];   // [B,Q,128,128]
    const float* osz    = (const float*)d_in[3];   // [B,2]
    // d_in[4]/d_in[5] = target_h/target_w (constant 320, baked in)

    float* out = (float*)d_out;
    int* qidx  = (int*)d_ws;                       // B*K ints

    topk_kernel<<<Bq, TPB, 0, stream>>>(logits, boxes, osz, out, qidx);
    resize_kernel<<<Bq * Kn * 4, 320, 0, stream>>>(masks, qidx, out);
}